// Round 1
// baseline (1959.798 us; speedup 1.0000x reference)
//
#include <hip/hip_runtime.h>
#include <math.h>

#define D_MODEL 1024
#define N_HEADS 16
#define D_KK    64
#define B_SZ    2
#define SEQ     2048
#define M_TOTAL (B_SZ * SEQ)   // 4096

// ---------------------------------------------------------------------------
// Tiled fp32 GEMM:  C[m,n] = sum_k A[m,k] * W[n,k] + bias[n]   (A:MxK, W:NxK)
// BM=BN=128, BK=16, 256 threads, 8x8 per thread (split 4+4 frags).
// grid.z selects among up to 3 (W,bias,C) triples (fused QKV).
// HEAD_SPLIT: store C as [b, h, s, d] (b=m/SEQ, s=m%SEQ, h=n/64, d=n%64).
// ---------------------------------------------------------------------------
template<bool HEAD_SPLIT>
__global__ __launch_bounds__(256)
void gemm3_kernel(const float* __restrict__ A,
                  const float* __restrict__ W0, const float* __restrict__ b0, float* __restrict__ C0,
                  const float* __restrict__ W1, const float* __restrict__ b1, float* __restrict__ C1,
                  const float* __restrict__ W2, const float* __restrict__ b2, float* __restrict__ C2)
{
    constexpr int K = D_MODEL;   // 1024
    constexpr int N = D_MODEL;   // 1024

    const float* W    = W0;
    const float* bias = b0;
    float*       C    = C0;
    if (blockIdx.z == 1) { W = W1; bias = b1; C = C1; }
    else if (blockIdx.z == 2) { W = W2; bias = b2; C = C2; }

    __shared__ float As[16][128];
    __shared__ float Bs[16][128];

    const int tid = threadIdx.x;
    const int tx  = tid & 15;          // 0..15
    const int ty  = tid >> 4;          // 0..15
    const int m0  = blockIdx.x * 128;
    const int n0  = blockIdx.y * 128;

    float acc[8][8];
#pragma unroll
    for (int i = 0; i < 8; ++i)
#pragma unroll
        for (int j = 0; j < 8; ++j) acc[i][j] = 0.0f;

    for (int k0 = 0; k0 < K; k0 += 16) {
        // Stage A tile (128 rows x 16 k) transposed into As[k][m]; 512 float4, 2/thread.
#pragma unroll
        for (int l = 0; l < 2; ++l) {
            int idx = tid + l * 256;           // 0..511
            int row = idx >> 2;                // 0..127
            int c4  = (idx & 3) * 4;           // 0,4,8,12
            float4 v = *reinterpret_cast<const float4*>(&A[(size_t)(m0 + row) * K + k0 + c4]);
            As[c4 + 0][row] = v.x; As[c4 + 1][row] = v.y;
            As[c4 + 2][row] = v.z; As[c4 + 3][row] = v.w;
        }
#pragma unroll
        for (int l = 0; l < 2; ++l) {
            int idx = tid + l * 256;
            int row = idx >> 2;
            int c4  = (idx & 3) * 4;
            float4 v = *reinterpret_cast<const float4*>(&W[(size_t)(n0 + row) * K + k0 + c4]);
            Bs[c4 + 0][row] = v.x; Bs[c4 + 1][row] = v.y;
            Bs[c4 + 2][row] = v.z; Bs[c4 + 3][row] = v.w;
        }
        __syncthreads();

#pragma unroll
        for (int kk = 0; kk < 16; ++kk) {
            float a[8], b[8];
            *reinterpret_cast<float4*>(&a[0]) = *reinterpret_cast<const float4*>(&As[kk][ty * 4]);
            *reinterpret_cast<float4*>(&a[4]) = *reinterpret_cast<const float4*>(&As[kk][64 + ty * 4]);
            *reinterpret_cast<float4*>(&b[0]) = *reinterpret_cast<const float4*>(&Bs[kk][tx * 4]);
            *reinterpret_cast<float4*>(&b[4]) = *reinterpret_cast<const float4*>(&Bs[kk][64 + tx * 4]);
#pragma unroll
            for (int i = 0; i < 8; ++i)
#pragma unroll
                for (int j = 0; j < 8; ++j)
                    acc[i][j] = fmaf(a[i], b[j], acc[i][j]);
        }
        __syncthreads();
    }

    // Epilogue
#pragma unroll
    for (int ih = 0; ih < 2; ++ih)
#pragma unroll
    for (int ii = 0; ii < 4; ++ii) {
        int m  = m0 + ih * 64 + ty * 4 + ii;
        int bb = m >> 11;          // m / SEQ
        int ss = m & 2047;         // m % SEQ
#pragma unroll
        for (int jh = 0; jh < 2; ++jh) {
            int n = n0 + jh * 64 + tx * 4;
            float4 bv = *reinterpret_cast<const float4*>(&bias[n]);
            float4 v;
            v.x = acc[ih * 4 + ii][jh * 4 + 0] + bv.x;
            v.y = acc[ih * 4 + ii][jh * 4 + 1] + bv.y;
            v.z = acc[ih * 4 + ii][jh * 4 + 2] + bv.z;
            v.w = acc[ih * 4 + ii][jh * 4 + 3] + bv.w;
            if (HEAD_SPLIT) {
                int h = n >> 6;
                int d = n & 63;
                *reinterpret_cast<float4*>(
                    &C[(((size_t)bb * N_HEADS + h) * SEQ + ss) * D_KK + d]) = v;
            } else {
                *reinterpret_cast<float4*>(&C[(size_t)m * N + n]) = v;
            }
        }
    }
}

// ---------------------------------------------------------------------------
// Causal flash attention (fp32). One thread per query row.
// Q/K/V layout: [b*H + h][s][64]. Output: [b][s][h*64 + d] (= [4096,1024]).
// grid: (SEQ/256, B*H), block: 256.
// ---------------------------------------------------------------------------
__global__ __launch_bounds__(256)
void attn_kernel(const float* __restrict__ Qw, const float* __restrict__ Kw,
                 const float* __restrict__ Vw, float* __restrict__ Ow)
{
    __shared__ float Ks[64][D_KK];
    __shared__ float Vs[64][D_KK];

    const int tid = threadIdx.x;
    const int qg  = blockIdx.x * 256 + tid;          // query index within sequence
    const int bh  = blockIdx.y;                      // b*H + h
    const int b   = bh >> 4;
    const int h   = bh & 15;

    const float* Qp    = Qw + ((size_t)bh * SEQ + qg) * D_KK;
    const float* Kbase = Kw + (size_t)bh * SEQ * D_KK;
    const float* Vbase = Vw + (size_t)bh * SEQ * D_KK;

    float q[D_KK];
#pragma unroll
    for (int i = 0; i < 16; ++i)
        *reinterpret_cast<float4*>(&q[i * 4]) =
            *reinterpret_cast<const float4*>(&Qp[i * 4]);

    float o[D_KK];
#pragma unroll
    for (int d = 0; d < D_KK; ++d) o[d] = 0.0f;
    float mmax = -1e30f;
    float lsum = 0.0f;

    const float scale = 0.125f;                      // 1/sqrt(64)
    const int kend = blockIdx.x * 256 + 256;         // keys needed by this block

    for (int k0 = 0; k0 < kend; k0 += 64) {
        __syncthreads();   // previous-tile readers done before overwrite
#pragma unroll
        for (int l4 = 0; l4 < 4; ++l4) {
            int idx = tid + l4 * 256;                // float4 index 0..1023
            int row = idx >> 4;                      // 0..63
            int col = (idx & 15) * 4;                // 0..60
            *reinterpret_cast<float4*>(&Ks[row][col]) =
                *reinterpret_cast<const float4*>(&Kbase[(size_t)(k0 + row) * D_KK + col]);
            *reinterpret_cast<float4*>(&Vs[row][col]) =
                *reinterpret_cast<const float4*>(&Vbase[(size_t)(k0 + row) * D_KK + col]);
        }
        __syncthreads();

        int nk = qg - k0 + 1;
        if (nk > 64) nk = 64;
        for (int kk = 0; kk < nk; ++kk) {
            float sp0 = 0.f, sp1 = 0.f, sp2 = 0.f, sp3 = 0.f;
            const float* krow = &Ks[kk][0];
#pragma unroll
            for (int d = 0; d < D_KK; d += 4) {
                sp0 = fmaf(q[d + 0], krow[d + 0], sp0);
                sp1 = fmaf(q[d + 1], krow[d + 1], sp1);
                sp2 = fmaf(q[d + 2], krow[d + 2], sp2);
                sp3 = fmaf(q[d + 3], krow[d + 3], sp3);
            }
            float s = ((sp0 + sp1) + (sp2 + sp3)) * scale;
            const float* vrow = &Vs[kk][0];
            if (s <= mmax) {                         // common path: no max update
                float p = __expf(s - mmax);
                lsum += p;
#pragma unroll
                for (int d = 0; d < D_KK; ++d)
                    o[d] = fmaf(p, vrow[d], o[d]);
            } else {                                 // rescale path (p == 1)
                float corr = __expf(mmax - s);
                mmax = s;
                lsum = fmaf(lsum, corr, 1.0f);
#pragma unroll
                for (int d = 0; d < D_KK; ++d)
                    o[d] = fmaf(o[d], corr, vrow[d]);
            }
        }
    }

    const float inv = 1.0f / lsum;
    float* Op = Ow + ((size_t)b * SEQ + qg) * D_MODEL + h * D_KK;
#pragma unroll
    for (int i = 0; i < 16; ++i) {
        float4 v;
        v.x = o[i * 4 + 0] * inv;
        v.y = o[i * 4 + 1] * inv;
        v.z = o[i * 4 + 2] * inv;
        v.w = o[i * 4 + 3] * inv;
        *reinterpret_cast<float4*>(&Op[i * 4]) = v;
    }
}

// ---------------------------------------------------------------------------
extern "C" void kernel_launch(void* const* d_in, const int* in_sizes, int n_in,
                              void* d_out, int out_size, void* d_ws, size_t ws_size,
                              hipStream_t stream)
{
    const float* x  = (const float*)d_in[0];
    // d_in[1] = causal mask (tril) — implemented analytically.
    const float* Wq = (const float*)d_in[2];
    const float* bq = (const float*)d_in[3];
    const float* Wk = (const float*)d_in[4];
    const float* bk = (const float*)d_in[5];
    const float* Wv = (const float*)d_in[6];
    const float* bv = (const float*)d_in[7];
    const float* Wo = (const float*)d_in[8];
    const float* bo = (const float*)d_in[9];
    float* out = (float*)d_out;

    const size_t TSZ = (size_t)M_TOTAL * D_MODEL;    // 4096*1024 floats
    float* Qw = (float*)d_ws;
    float* Kw = Qw + TSZ;
    float* Vw = Kw + TSZ;
    float* Aw = Vw + TSZ;                            // total 64 MiB

    dim3 blk(256);
    dim3 g_qkv(M_TOTAL / 128, D_MODEL / 128, 3);
    gemm3_kernel<true><<<g_qkv, blk, 0, stream>>>(x, Wq, bq, Qw, Wk, bk, Kw, Wv, bv, Vw);

    dim3 g_at(SEQ / 256, B_SZ * N_HEADS);
    attn_kernel<<<g_at, blk, 0, stream>>>(Qw, Kw, Vw, Aw);

    dim3 g_o(M_TOTAL / 128, D_MODEL / 128, 1);
    gemm3_kernel<false><<<g_o, blk, 0, stream>>>(Aw, Wo, bo, out, Wo, bo, out, Wo, bo, out);
}

// Round 2
// 586.637 us; speedup vs baseline: 3.3407x; 3.3407x over previous
//
#include <hip/hip_runtime.h>
#include <math.h>

#define D_MODEL 1024
#define N_HEADS 16
#define D_KK    64
#define B_SZ    2
#define SEQ     2048
#define M_TOTAL (B_SZ * SEQ)   // 4096

typedef __attribute__((ext_vector_type(8))) short short8;
typedef __attribute__((ext_vector_type(4))) float f32x4;

static __device__ __forceinline__ ushort f2bf(float f) {
    union { float f; unsigned u; } c; c.f = f;
    unsigned u = c.u;
    unsigned r = (u + 0x7fffu + ((u >> 16) & 1u)) >> 16;   // RNE
    return (ushort)r;
}

// ---------------------------------------------------------------------------
// Tiled fp32 GEMM:  C[m,n] = sum_k A[m,k] * W[n,k] + bias[n]   (A:MxK, W:NxK)
// BM=BN=128, BK=16, 256 threads, 8x8 per thread.
// EPI=0: fp32 C[m][n].
// EPI=1: fused QKV; z=0,1 -> bf16 head-split [bh][s][64]; z=2 -> bf16 V^T [bh][64][s].
// ---------------------------------------------------------------------------
template<int EPI>
__global__ __launch_bounds__(256)
void gemm3_kernel(const float* __restrict__ A,
                  const float* __restrict__ W0, const float* __restrict__ b0, float* __restrict__ C0,
                  const float* __restrict__ W1, const float* __restrict__ b1, float* __restrict__ C1,
                  const float* __restrict__ W2, const float* __restrict__ b2, float* __restrict__ C2)
{
    constexpr int K = D_MODEL;
    constexpr int N = D_MODEL;

    const float* W    = W0;
    const float* bias = b0;
    float*       C    = C0;
    if (blockIdx.z == 1) { W = W1; bias = b1; C = C1; }
    else if (blockIdx.z == 2) { W = W2; bias = b2; C = C2; }

    __shared__ float As[16][128];
    __shared__ float Bs[16][128];

    const int tid = threadIdx.x;
    const int tx  = tid & 15;
    const int ty  = tid >> 4;
    const int m0  = blockIdx.x * 128;
    const int n0  = blockIdx.y * 128;

    float acc[8][8];
#pragma unroll
    for (int i = 0; i < 8; ++i)
#pragma unroll
        for (int j = 0; j < 8; ++j) acc[i][j] = 0.0f;

    for (int k0 = 0; k0 < K; k0 += 16) {
#pragma unroll
        for (int l = 0; l < 2; ++l) {
            int idx = tid + l * 256;
            int row = idx >> 2;
            int c4  = (idx & 3) * 4;
            float4 v = *reinterpret_cast<const float4*>(&A[(size_t)(m0 + row) * K + k0 + c4]);
            As[c4 + 0][row] = v.x; As[c4 + 1][row] = v.y;
            As[c4 + 2][row] = v.z; As[c4 + 3][row] = v.w;
        }
#pragma unroll
        for (int l = 0; l < 2; ++l) {
            int idx = tid + l * 256;
            int row = idx >> 2;
            int c4  = (idx & 3) * 4;
            float4 v = *reinterpret_cast<const float4*>(&W[(size_t)(n0 + row) * K + k0 + c4]);
            Bs[c4 + 0][row] = v.x; Bs[c4 + 1][row] = v.y;
            Bs[c4 + 2][row] = v.z; Bs[c4 + 3][row] = v.w;
        }
        __syncthreads();

#pragma unroll
        for (int kk = 0; kk < 16; ++kk) {
            float a[8], b[8];
            *reinterpret_cast<float4*>(&a[0]) = *reinterpret_cast<const float4*>(&As[kk][ty * 4]);
            *reinterpret_cast<float4*>(&a[4]) = *reinterpret_cast<const float4*>(&As[kk][64 + ty * 4]);
            *reinterpret_cast<float4*>(&b[0]) = *reinterpret_cast<const float4*>(&Bs[kk][tx * 4]);
            *reinterpret_cast<float4*>(&b[4]) = *reinterpret_cast<const float4*>(&Bs[kk][64 + tx * 4]);
#pragma unroll
            for (int i = 0; i < 8; ++i)
#pragma unroll
                for (int j = 0; j < 8; ++j)
                    acc[i][j] = fmaf(a[i], b[j], acc[i][j]);
        }
        __syncthreads();
    }

#pragma unroll
    for (int ih = 0; ih < 2; ++ih)
#pragma unroll
    for (int ii = 0; ii < 4; ++ii) {
        int m  = m0 + ih * 64 + ty * 4 + ii;
        int bb = m >> 11;
        int ss = m & 2047;
#pragma unroll
        for (int jh = 0; jh < 2; ++jh) {
            int n = n0 + jh * 64 + tx * 4;
            float4 bv = *reinterpret_cast<const float4*>(&bias[n]);
            float4 v;
            v.x = acc[ih * 4 + ii][jh * 4 + 0] + bv.x;
            v.y = acc[ih * 4 + ii][jh * 4 + 1] + bv.y;
            v.z = acc[ih * 4 + ii][jh * 4 + 2] + bv.z;
            v.w = acc[ih * 4 + ii][jh * 4 + 3] + bv.w;
            if (EPI == 1) {
                int h = n >> 6;
                int d = n & 63;
                size_t bh = (size_t)bb * N_HEADS + h;
                if (blockIdx.z == 2) {            // V^T : [bh][64][SEQ]
                    ushort* VT = (ushort*)C;
                    VT[(bh * D_KK + d + 0) * SEQ + ss] = f2bf(v.x);
                    VT[(bh * D_KK + d + 1) * SEQ + ss] = f2bf(v.y);
                    VT[(bh * D_KK + d + 2) * SEQ + ss] = f2bf(v.z);
                    VT[(bh * D_KK + d + 3) * SEQ + ss] = f2bf(v.w);
                } else {                          // Q/K : [bh][SEQ][64]
                    ushort4 u;
                    u.x = f2bf(v.x); u.y = f2bf(v.y); u.z = f2bf(v.z); u.w = f2bf(v.w);
                    *reinterpret_cast<ushort4*>(
                        &((ushort*)C)[(bh * SEQ + ss) * D_KK + d]) = u;
                }
            } else {
                *reinterpret_cast<float4*>(&C[(size_t)m * N + n]) = v;
            }
        }
    }
}

// ---------------------------------------------------------------------------
// MFMA flash attention (bf16 in, fp32 accum). 4 waves/block, wave owns 16 q rows.
// Q,K: [bh][s][64] bf16.  Vt: [bh][64][s] bf16.  Out: [b][s][h*64+d] fp32.
// grid: (16, B*H); block(i) handles q-blocks {i, 31-i} (balanced causal work).
// No __syncthreads: frags loaded from global (L2-resident), P via per-wave LDS.
// ---------------------------------------------------------------------------
__global__ __launch_bounds__(256)
void attn_mfma_kernel(const ushort* __restrict__ Qb, const ushort* __restrict__ Kb,
                      const ushort* __restrict__ Vt, float* __restrict__ Ow)
{
    __shared__ ushort P_lds[4][1024];   // per-wave 16x64 bf16, XOR-swizzled

    const int tid  = threadIdx.x;
    const int w    = tid >> 6;
    const int lane = tid & 63;
    const int lr   = lane & 15;          // frag row / col index
    const int lc   = lane >> 4;          // frag k-chunk index
    const int bh   = blockIdx.y;
    const int b    = bh >> 4;
    const int h    = bh & 15;

    ushort* Pw = &P_lds[w][0];
    const int sw_w = (lr & 7) << 4;      // read-side XOR (byte)

    for (int half = 0; half < 2; ++half) {
        const int qb  = half ? (31 - (int)blockIdx.x) : (int)blockIdx.x;
        const int q0  = qb * 64;
        const int qr0 = q0 + w * 16;

        const ushort* Qp = Qb + ((size_t)bh * SEQ + qr0 + lr) * D_KK + lc * 8;
        const short8 qa0 = *reinterpret_cast<const short8*>(Qp);
        const short8 qa1 = *reinterpret_cast<const short8*>(Qp + 32);

        f32x4 acc_o[4];
        float m_run[4], l_run[4];
#pragma unroll
        for (int t = 0; t < 4; ++t) acc_o[t] = (f32x4)0.0f;
#pragma unroll
        for (int r = 0; r < 4; ++r) { m_run[r] = -1e30f; l_run[r] = 0.0f; }

        for (int k0 = 0; k0 <= q0; k0 += 64) {
            // ---- S = Q K^T (16 x 64), 8 MFMA ----
            f32x4 s[4];
#pragma unroll
            for (int t = 0; t < 4; ++t) {
                const ushort* Kp = Kb + ((size_t)bh * SEQ + k0 + t * 16 + lr) * D_KK + lc * 8;
                f32x4 a = (f32x4)0.0f;
                a = __builtin_amdgcn_mfma_f32_16x16x32_bf16(
                        qa0, *reinterpret_cast<const short8*>(Kp), a, 0, 0, 0);
                a = __builtin_amdgcn_mfma_f32_16x16x32_bf16(
                        qa1, *reinterpret_cast<const short8*>(Kp + 32), a, 0, 0, 0);
                s[t] = a;
            }

            // ---- scale + causal mask + online softmax ----
            const bool needmask = (k0 + 63 > qr0);
            float mx[4], rs[4];
#pragma unroll
            for (int r = 0; r < 4; ++r) {
                const int qrow = qr0 + lc * 4 + r;
                float best = -1e30f;
#pragma unroll
                for (int t = 0; t < 4; ++t) {
                    float v = s[t][r] * 0.125f;
                    if (needmask && (k0 + t * 16 + lr > qrow)) v = -1e30f;
                    s[t][r] = v;
                    best = fmaxf(best, v);
                }
                mx[r] = best;
            }
#pragma unroll
            for (int off = 1; off < 16; off <<= 1)
#pragma unroll
                for (int r = 0; r < 4; ++r)
                    mx[r] = fmaxf(mx[r], __shfl_xor(mx[r], off));

#pragma unroll
            for (int r = 0; r < 4; ++r) {
                const float mn   = fmaxf(m_run[r], mx[r]);
                const float corr = __expf(m_run[r] - mn);
                m_run[r] = mn;
                l_run[r] *= corr;
                acc_o[0][r] *= corr; acc_o[1][r] *= corr;
                acc_o[2][r] *= corr; acc_o[3][r] *= corr;
                float sum = 0.0f;
#pragma unroll
                for (int t = 0; t < 4; ++t) {
                    float p = __expf(s[t][r] - mn);
                    s[t][r] = p;
                    sum += p;
                }
                rs[r] = sum;
            }
#pragma unroll
            for (int off = 1; off < 16; off <<= 1)
#pragma unroll
                for (int r = 0; r < 4; ++r)
                    rs[r] += __shfl_xor(rs[r], off);
#pragma unroll
            for (int r = 0; r < 4; ++r) l_run[r] += rs[r];

            // ---- P -> LDS (bf16, XOR-swizzled rows of 128B) ----
#pragma unroll
            for (int r = 0; r < 4; ++r) {
                const int row = lc * 4 + r;
                const int sw  = (row & 7) << 4;
#pragma unroll
                for (int t = 0; t < 4; ++t) {
                    const int byte = row * 128 + ((((t * 16 + lr) * 2)) ^ sw);
                    Pw[byte >> 1] = f2bf(s[t][r]);
                }
            }
            // ---- PA frags (this wave's own region; in-order, no barrier) ----
            const short8 pa0 = *reinterpret_cast<const short8*>(
                &Pw[(lr * 128 + ((lc * 16) ^ sw_w)) >> 1]);
            const short8 pa1 = *reinterpret_cast<const short8*>(
                &Pw[(lr * 128 + ((64 + lc * 16) ^ sw_w)) >> 1]);

            // ---- O += P V (16 x 64), 8 MFMA ----
            const ushort* Vp = Vt + (size_t)bh * D_KK * SEQ + k0 + lc * 8;
#pragma unroll
            for (int t = 0; t < 4; ++t) {
                const ushort* Vr = Vp + (size_t)(t * 16 + lr) * SEQ;
                acc_o[t] = __builtin_amdgcn_mfma_f32_16x16x32_bf16(
                        pa0, *reinterpret_cast<const short8*>(Vr), acc_o[t], 0, 0, 0);
                acc_o[t] = __builtin_amdgcn_mfma_f32_16x16x32_bf16(
                        pa1, *reinterpret_cast<const short8*>(Vr + 32), acc_o[t], 0, 0, 0);
            }
        }

        // ---- normalize + store ----
#pragma unroll
        for (int r = 0; r < 4; ++r) {
            const float inv  = 1.0f / l_run[r];
            const int   qrow = qr0 + lc * 4 + r;
            float* Op = Ow + ((size_t)b * SEQ + qrow) * D_MODEL + h * D_KK;
#pragma unroll
            for (int t = 0; t < 4; ++t)
                Op[t * 16 + lr] = acc_o[t][r] * inv;
        }
    }
}

// ---------------------------------------------------------------------------
extern "C" void kernel_launch(void* const* d_in, const int* in_sizes, int n_in,
                              void* d_out, int out_size, void* d_ws, size_t ws_size,
                              hipStream_t stream)
{
    const float* x  = (const float*)d_in[0];
    const float* Wq = (const float*)d_in[2];
    const float* bq = (const float*)d_in[3];
    const float* Wk = (const float*)d_in[4];
    const float* bk = (const float*)d_in[5];
    const float* Wv = (const float*)d_in[6];
    const float* bv = (const float*)d_in[7];
    const float* Wo = (const float*)d_in[8];
    const float* bo = (const float*)d_in[9];
    float* out = (float*)d_out;

    const size_t TSZ = (size_t)M_TOTAL * D_MODEL;    // elements per tensor
    ushort* Qb = (ushort*)d_ws;                      // 8 MB
    ushort* Kb = Qb + TSZ;                           // 8 MB
    ushort* Vt = Kb + TSZ;                           // 8 MB
    float*  Aw = (float*)(Vt + TSZ);                 // 16 MB

    dim3 blk(256);
    dim3 g_qkv(M_TOTAL / 128, D_MODEL / 128, 3);
    gemm3_kernel<1><<<g_qkv, blk, 0, stream>>>(x, Wq, bq, (float*)Qb,
                                                  Wk, bk, (float*)Kb,
                                                  Wv, bv, (float*)Vt);

    dim3 g_at(16, B_SZ * N_HEADS);
    attn_mfma_kernel<<<g_at, blk, 0, stream>>>(Qb, Kb, Vt, Aw);

    dim3 g_o(M_TOTAL / 128, D_MODEL / 128, 1);
    gemm3_kernel<0><<<g_o, blk, 0, stream>>>(Aw, Wo, bo, out, Wo, bo, out, Wo, bo, out);
}

// Round 3
// 202.870 us; speedup vs baseline: 9.6603x; 2.8917x over previous
//
#include <hip/hip_runtime.h>
#include <math.h>

#define D_MODEL 1024
#define N_HEADS 16
#define D_KK    64
#define B_SZ    2
#define SEQ     2048
#define M_TOTAL (B_SZ * SEQ)   // 4096

typedef __attribute__((ext_vector_type(8))) short short8;
typedef __attribute__((ext_vector_type(4))) float f32x4;

static __device__ __forceinline__ ushort f2bf(float f) {
    union { float f; unsigned u; } c; c.f = f;
    unsigned u = c.u;
    unsigned r = (u + 0x7fffu + ((u >> 16) & 1u)) >> 16;   // RNE
    return (ushort)r;
}

static __device__ __forceinline__ void gload16(const void* g, void* l) {
    __builtin_amdgcn_global_load_lds(
        (const __attribute__((address_space(1))) void*)g,
        (__attribute__((address_space(3))) void*)l, 16, 0, 0);
}

// ---------------------------------------------------------------------------
// fp32 -> bf16 conversion: x and the four weight matrices.
// ---------------------------------------------------------------------------
__global__ __launch_bounds__(256)
void cvt_kernel(const float* __restrict__ x,  const float* __restrict__ wq,
                const float* __restrict__ wk, const float* __restrict__ wv,
                const float* __restrict__ wo,
                ushort* __restrict__ xb,  ushort* __restrict__ wqb,
                ushort* __restrict__ wkb, ushort* __restrict__ wvb,
                ushort* __restrict__ wob)
{
    const float* s; ushort* d; int n4;
    switch (blockIdx.y) {
        case 0:  s = x;  d = xb;  n4 = M_TOTAL * D_MODEL / 4; break;
        case 1:  s = wq; d = wqb; n4 = D_MODEL * D_MODEL / 4; break;
        case 2:  s = wk; d = wkb; n4 = D_MODEL * D_MODEL / 4; break;
        case 3:  s = wv; d = wvb; n4 = D_MODEL * D_MODEL / 4; break;
        default: s = wo; d = wob; n4 = D_MODEL * D_MODEL / 4; break;
    }
    const int stride = gridDim.x * blockDim.x;
    for (int i = blockIdx.x * blockDim.x + threadIdx.x; i < n4; i += stride) {
        float4 v = reinterpret_cast<const float4*>(s)[i];
        ushort4 u;
        u.x = f2bf(v.x); u.y = f2bf(v.y); u.z = f2bf(v.z); u.w = f2bf(v.w);
        reinterpret_cast<ushort4*>(d)[i] = u;
    }
}

// ---------------------------------------------------------------------------
// bf16 MFMA GEMM (m97 structure): C[m,n] = sum_k A[m,k]*W[n,k] + bias[n]
// 128x128 tile, BK=32, 256 thr (4 waves, 2x2), 4x4 16x16 frags/wave.
// global->LDS via global_load_lds width=16 (linear dest), 2-barrier K-loop.
// EPI=0: fp32 C[m][N].  EPI=1: z=0,1 -> bf16 [bh][s][64]; z=2 -> bf16 V^T [bh][64][s].
// ---------------------------------------------------------------------------
template<int EPI>
__global__ __launch_bounds__(256)
void gemm_mfma(const ushort* __restrict__ A,
               const ushort* __restrict__ W0, const float* __restrict__ b0, void* __restrict__ C0,
               const ushort* __restrict__ W1, const float* __restrict__ b1, void* __restrict__ C1,
               const ushort* __restrict__ W2, const float* __restrict__ b2, void* __restrict__ C2)
{
    constexpr int K = D_MODEL;

    const ushort* W    = W0;
    const float*  bias = b0;
    void*         C    = C0;
    if (blockIdx.z == 1) { W = W1; bias = b1; C = C1; }
    else if (blockIdx.z == 2) { W = W2; bias = b2; C = C2; }

    __shared__ ushort As[128 * 32];
    __shared__ ushort Bs[128 * 32];

    const int tid  = threadIdx.x;
    const int w    = tid >> 6;
    const int lane = tid & 63;
    const int lr   = lane & 15;
    const int lc   = lane >> 4;
    const int wr   = w >> 1;
    const int wc   = w & 1;
    const int m0   = blockIdx.x * 128;
    const int n0   = blockIdx.y * 128;

    // staging: wave w owns LDS regions {2w, 2w+1} of 1024B (16 rows x 64B) each
    const int srow = lane >> 2;          // row within 16-row region
    const int scol = (lane & 3) * 8;     // bf16 col within 32
    const int g0   = w * 2;

    const ushort* gA = A + (size_t)(m0 + g0 * 16 + srow) * K + scol;
    const ushort* gB = W + (size_t)(n0 + g0 * 16 + srow) * K + scol;
    ushort* lA = &As[g0 * 512];          // wave-uniform LDS bases
    ushort* lB = &Bs[g0 * 512];

    f32x4 acc[4][4];
#pragma unroll
    for (int m = 0; m < 4; ++m)
#pragma unroll
        for (int n = 0; n < 4; ++n) acc[m][n] = (f32x4)0.0f;

    for (int k0 = 0; k0 < K; k0 += 32) {
        gload16(gA + k0,          lA);
        gload16(gA + k0 + 16 * K, lA + 512);
        gload16(gB + k0,          lB);
        gload16(gB + k0 + 16 * K, lB + 512);
        __syncthreads();                 // drains vmcnt before barrier

        short8 af[4], bfr[4];
#pragma unroll
        for (int m = 0; m < 4; ++m)
            af[m] = *reinterpret_cast<const short8*>(
                &As[(wr * 64 + m * 16 + lr) * 32 + lc * 8]);
#pragma unroll
        for (int n = 0; n < 4; ++n)
            bfr[n] = *reinterpret_cast<const short8*>(
                &Bs[(wc * 64 + n * 16 + lr) * 32 + lc * 8]);
#pragma unroll
        for (int m = 0; m < 4; ++m)
#pragma unroll
            for (int n = 0; n < 4; ++n)
                acc[m][n] = __builtin_amdgcn_mfma_f32_16x16x32_bf16(
                    af[m], bfr[n], acc[m][n], 0, 0, 0);
        __syncthreads();
    }

    // epilogue: C row = m0+wr*64+m*16+lc*4+r ; col = n0+wc*64+n*16+lr
    float bv[4];
#pragma unroll
    for (int n = 0; n < 4; ++n) bv[n] = bias[n0 + wc * 64 + n * 16 + lr];
    const int row_base = m0 + wr * 64;

    if (EPI == 0) {
        float* Cf = (float*)C;
#pragma unroll
        for (int m = 0; m < 4; ++m)
#pragma unroll
        for (int r = 0; r < 4; ++r) {
            const int row = row_base + m * 16 + lc * 4 + r;
#pragma unroll
            for (int n = 0; n < 4; ++n)
                Cf[(size_t)row * D_MODEL + n0 + wc * 64 + n * 16 + lr] =
                    acc[m][n][r] + bv[n];
        }
    } else {
        ushort* Cu = (ushort*)C;
        const bool vt = (blockIdx.z == 2);
#pragma unroll
        for (int m = 0; m < 4; ++m) {
            const int row4 = row_base + m * 16 + lc * 4;   // 4 consecutive rows
            const int bb = row4 >> 11;
            const int ss = row4 & 2047;
            const size_t bhbase = (size_t)bb * N_HEADS;
#pragma unroll
            for (int n = 0; n < 4; ++n) {
                const int col = n0 + wc * 64 + n * 16 + lr;
                const int h = col >> 6, d = col & 63;
                if (vt) {                       // V^T : [bh][64][SEQ], 4 consecutive ss
                    ushort4 u;
                    u.x = f2bf(acc[m][n][0] + bv[n]);
                    u.y = f2bf(acc[m][n][1] + bv[n]);
                    u.z = f2bf(acc[m][n][2] + bv[n]);
                    u.w = f2bf(acc[m][n][3] + bv[n]);
                    *reinterpret_cast<ushort4*>(
                        &Cu[((bhbase + h) * D_KK + d) * SEQ + ss]) = u;
                } else {                        // Q/K : [bh][SEQ][64]
#pragma unroll
                    for (int r = 0; r < 4; ++r)
                        Cu[((bhbase + h) * SEQ + ss + r) * D_KK + d] =
                            f2bf(acc[m][n][r] + bv[n]);
                }
            }
        }
    }
}

// ---------------------------------------------------------------------------
// MFMA flash attention (bf16 in, fp32 accum, bf16 out). 4 waves/block.
// Q,K: [bh][s][64] bf16.  Vt: [bh][64][s] bf16.  Out: [b][s][h*64+d] bf16.
// grid: (16, B*H); block(i) handles q-blocks {i, 31-i}.
// ---------------------------------------------------------------------------
__global__ __launch_bounds__(256)
void attn_mfma_kernel(const ushort* __restrict__ Qb, const ushort* __restrict__ Kb,
                      const ushort* __restrict__ Vt, ushort* __restrict__ Ob)
{
    __shared__ ushort P_lds[4][1024];   // per-wave 16x64 bf16, XOR-swizzled

    const int tid  = threadIdx.x;
    const int w    = tid >> 6;
    const int lane = tid & 63;
    const int lr   = lane & 15;
    const int lc   = lane >> 4;
    const int bh   = blockIdx.y;
    const int b    = bh >> 4;
    const int h    = bh & 15;

    ushort* Pw = &P_lds[w][0];
    const int sw_w = (lr & 7) << 4;

    for (int half = 0; half < 2; ++half) {
        const int qb  = half ? (31 - (int)blockIdx.x) : (int)blockIdx.x;
        const int q0  = qb * 64;
        const int qr0 = q0 + w * 16;

        const ushort* Qp = Qb + ((size_t)bh * SEQ + qr0 + lr) * D_KK + lc * 8;
        const short8 qa0 = *reinterpret_cast<const short8*>(Qp);
        const short8 qa1 = *reinterpret_cast<const short8*>(Qp + 32);

        f32x4 acc_o[4];
        float m_run[4], l_run[4];
#pragma unroll
        for (int t = 0; t < 4; ++t) acc_o[t] = (f32x4)0.0f;
#pragma unroll
        for (int r = 0; r < 4; ++r) { m_run[r] = -1e30f; l_run[r] = 0.0f; }

        for (int k0 = 0; k0 <= q0; k0 += 64) {
            f32x4 s[4];
#pragma unroll
            for (int t = 0; t < 4; ++t) {
                const ushort* Kp = Kb + ((size_t)bh * SEQ + k0 + t * 16 + lr) * D_KK + lc * 8;
                f32x4 a = (f32x4)0.0f;
                a = __builtin_amdgcn_mfma_f32_16x16x32_bf16(
                        qa0, *reinterpret_cast<const short8*>(Kp), a, 0, 0, 0);
                a = __builtin_amdgcn_mfma_f32_16x16x32_bf16(
                        qa1, *reinterpret_cast<const short8*>(Kp + 32), a, 0, 0, 0);
                s[t] = a;
            }

            const bool needmask = (k0 + 63 > qr0);
            float mx[4], rs[4];
#pragma unroll
            for (int r = 0; r < 4; ++r) {
                const int qrow = qr0 + lc * 4 + r;
                float best = -1e30f;
#pragma unroll
                for (int t = 0; t < 4; ++t) {
                    float v = s[t][r] * 0.125f;
                    if (needmask && (k0 + t * 16 + lr > qrow)) v = -1e30f;
                    s[t][r] = v;
                    best = fmaxf(best, v);
                }
                mx[r] = best;
            }
#pragma unroll
            for (int off = 1; off < 16; off <<= 1)
#pragma unroll
                for (int r = 0; r < 4; ++r)
                    mx[r] = fmaxf(mx[r], __shfl_xor(mx[r], off));

#pragma unroll
            for (int r = 0; r < 4; ++r) {
                const float mn   = fmaxf(m_run[r], mx[r]);
                const float corr = __expf(m_run[r] - mn);
                m_run[r] = mn;
                l_run[r] *= corr;
                acc_o[0][r] *= corr; acc_o[1][r] *= corr;
                acc_o[2][r] *= corr; acc_o[3][r] *= corr;
                float sum = 0.0f;
#pragma unroll
                for (int t = 0; t < 4; ++t) {
                    float p = __expf(s[t][r] - mn);
                    s[t][r] = p;
                    sum += p;
                }
                rs[r] = sum;
            }
#pragma unroll
            for (int off = 1; off < 16; off <<= 1)
#pragma unroll
                for (int r = 0; r < 4; ++r)
                    rs[r] += __shfl_xor(rs[r], off);
#pragma unroll
            for (int r = 0; r < 4; ++r) l_run[r] += rs[r];

#pragma unroll
            for (int r = 0; r < 4; ++r) {
                const int row = lc * 4 + r;
                const int sw  = (row & 7) << 4;
#pragma unroll
                for (int t = 0; t < 4; ++t) {
                    const int byte = row * 128 + ((((t * 16 + lr) * 2)) ^ sw);
                    Pw[byte >> 1] = f2bf(s[t][r]);
                }
            }
            const short8 pa0 = *reinterpret_cast<const short8*>(
                &Pw[(lr * 128 + ((lc * 16) ^ sw_w)) >> 1]);
            const short8 pa1 = *reinterpret_cast<const short8*>(
                &Pw[(lr * 128 + ((64 + lc * 16) ^ sw_w)) >> 1]);

            const ushort* Vp = Vt + (size_t)bh * D_KK * SEQ + k0 + lc * 8;
#pragma unroll
            for (int t = 0; t < 4; ++t) {
                const ushort* Vr = Vp + (size_t)(t * 16 + lr) * SEQ;
                acc_o[t] = __builtin_amdgcn_mfma_f32_16x16x32_bf16(
                        pa0, *reinterpret_cast<const short8*>(Vr), acc_o[t], 0, 0, 0);
                acc_o[t] = __builtin_amdgcn_mfma_f32_16x16x32_bf16(
                        pa1, *reinterpret_cast<const short8*>(Vr + 32), acc_o[t], 0, 0, 0);
            }
        }

#pragma unroll
        for (int r = 0; r < 4; ++r) {
            const float inv  = 1.0f / l_run[r];
            const int   qrow = qr0 + lc * 4 + r;
            ushort* Op = Ob + ((size_t)b * SEQ + qrow) * D_MODEL + h * D_KK;
#pragma unroll
            for (int t = 0; t < 4; ++t)
                Op[t * 16 + lr] = f2bf(acc_o[t][r] * inv);
        }
    }
}

// ---------------------------------------------------------------------------
extern "C" void kernel_launch(void* const* d_in, const int* in_sizes, int n_in,
                              void* d_out, int out_size, void* d_ws, size_t ws_size,
                              hipStream_t stream)
{
    const float* x  = (const float*)d_in[0];
    const float* Wq = (const float*)d_in[2];
    const float* bq = (const float*)d_in[3];
    const float* Wk = (const float*)d_in[4];
    const float* bk = (const float*)d_in[5];
    const float* Wv = (const float*)d_in[6];
    const float* bv = (const float*)d_in[7];
    const float* Wo = (const float*)d_in[8];
    const float* bo = (const float*)d_in[9];
    float* out = (float*)d_out;

    const size_t TSZ = (size_t)M_TOTAL * D_MODEL;    // 4M elements
    const size_t WSZ = (size_t)D_MODEL * D_MODEL;    // 1M elements
    ushort* xb  = (ushort*)d_ws;          // 8 MB
    ushort* Wqb = xb  + TSZ;              // 2 MB
    ushort* Wkb = Wqb + WSZ;
    ushort* Wvb = Wkb + WSZ;
    ushort* Wob = Wvb + WSZ;
    ushort* Qb  = Wob + WSZ;              // 8 MB
    ushort* Kb  = Qb  + TSZ;              // 8 MB
    ushort* Vt  = Kb  + TSZ;              // 8 MB
    ushort* Ob  = Vt  + TSZ;              // 8 MB   (total 48 MB)

    dim3 blk(256);
    cvt_kernel<<<dim3(256, 5), blk, 0, stream>>>(x, Wq, Wk, Wv, Wo,
                                                 xb, Wqb, Wkb, Wvb, Wob);

    dim3 g_qkv(M_TOTAL / 128, D_MODEL / 128, 3);
    gemm_mfma<1><<<g_qkv, blk, 0, stream>>>(xb, Wqb, bq, Qb,
                                                Wkb, bk, Kb,
                                                Wvb, bv, Vt);

    dim3 g_at(16, B_SZ * N_HEADS);
    attn_mfma_kernel<<<g_at, blk, 0, stream>>>(Qb, Kb, Vt, Ob);

    dim3 g_o(M_TOTAL / 128, D_MODEL / 128, 1);
    gemm_mfma<0><<<g_o, blk, 0, stream>>>(Ob, Wob, bo, out, Wob, bo, out, Wob, bo, out);
}

// Round 4
// 153.815 us; speedup vs baseline: 12.7413x; 1.3189x over previous
//
#include <hip/hip_runtime.h>
#include <math.h>

#define D_MODEL 1024
#define N_HEADS 16
#define D_KK    64
#define B_SZ    2
#define SEQ     2048
#define M_TOTAL (B_SZ * SEQ)   // 4096

typedef __attribute__((ext_vector_type(8))) short short8;
typedef __attribute__((ext_vector_type(4))) float f32x4;

static __device__ __forceinline__ ushort f2bf(float f) {
    union { float f; unsigned u; } c; c.f = f;
    unsigned u = c.u;
    unsigned r = (u + 0x7fffu + ((u >> 16) & 1u)) >> 16;   // RNE
    return (ushort)r;
}

static __device__ __forceinline__ void gload16(const void* g, void* l) {
    __builtin_amdgcn_global_load_lds(
        (const __attribute__((address_space(1))) void*)g,
        (__attribute__((address_space(3))) void*)l, 16, 0, 0);
}

// ---------------------------------------------------------------------------
// fp32 -> bf16 conversion: x and the four weight matrices.
// ---------------------------------------------------------------------------
__global__ __launch_bounds__(256)
void cvt_kernel(const float* __restrict__ x,  const float* __restrict__ wq,
                const float* __restrict__ wk, const float* __restrict__ wv,
                const float* __restrict__ wo,
                ushort* __restrict__ xb,  ushort* __restrict__ wqb,
                ushort* __restrict__ wkb, ushort* __restrict__ wvb,
                ushort* __restrict__ wob)
{
    const float* s; ushort* d; int n4;
    switch (blockIdx.y) {
        case 0:  s = x;  d = xb;  n4 = M_TOTAL * D_MODEL / 4; break;
        case 1:  s = wq; d = wqb; n4 = D_MODEL * D_MODEL / 4; break;
        case 2:  s = wk; d = wkb; n4 = D_MODEL * D_MODEL / 4; break;
        case 3:  s = wv; d = wvb; n4 = D_MODEL * D_MODEL / 4; break;
        default: s = wo; d = wob; n4 = D_MODEL * D_MODEL / 4; break;
    }
    const int stride = gridDim.x * blockDim.x;
    for (int i = blockIdx.x * blockDim.x + threadIdx.x; i < n4; i += stride) {
        float4 v = reinterpret_cast<const float4*>(s)[i];
        ushort4 u;
        u.x = f2bf(v.x); u.y = f2bf(v.y); u.z = f2bf(v.z); u.w = f2bf(v.w);
        reinterpret_cast<ushort4*>(d)[i] = u;
    }
}

// ---------------------------------------------------------------------------
// bf16 MFMA GEMM (m97 structure): C[m,n] = sum_k A[m,k]*W[n,k] + bias[n]
// ---------------------------------------------------------------------------
template<int EPI>
__global__ __launch_bounds__(256)
void gemm_mfma(const ushort* __restrict__ A,
               const ushort* __restrict__ W0, const float* __restrict__ b0, void* __restrict__ C0,
               const ushort* __restrict__ W1, const float* __restrict__ b1, void* __restrict__ C1,
               const ushort* __restrict__ W2, const float* __restrict__ b2, void* __restrict__ C2)
{
    constexpr int K = D_MODEL;

    const ushort* W    = W0;
    const float*  bias = b0;
    void*         C    = C0;
    if (blockIdx.z == 1) { W = W1; bias = b1; C = C1; }
    else if (blockIdx.z == 2) { W = W2; bias = b2; C = C2; }

    __shared__ ushort As[128 * 32];
    __shared__ ushort Bs[128 * 32];

    const int tid  = threadIdx.x;
    const int w    = tid >> 6;
    const int lane = tid & 63;
    const int lr   = lane & 15;
    const int lc   = lane >> 4;
    const int wr   = w >> 1;
    const int wc   = w & 1;
    const int m0   = blockIdx.x * 128;
    const int n0   = blockIdx.y * 128;

    const int srow = lane >> 2;
    const int scol = (lane & 3) * 8;
    const int g0   = w * 2;

    const ushort* gA = A + (size_t)(m0 + g0 * 16 + srow) * K + scol;
    const ushort* gB = W + (size_t)(n0 + g0 * 16 + srow) * K + scol;
    ushort* lA = &As[g0 * 512];
    ushort* lB = &Bs[g0 * 512];

    f32x4 acc[4][4];
#pragma unroll
    for (int m = 0; m < 4; ++m)
#pragma unroll
        for (int n = 0; n < 4; ++n) acc[m][n] = (f32x4)0.0f;

    for (int k0 = 0; k0 < K; k0 += 32) {
        gload16(gA + k0,          lA);
        gload16(gA + k0 + 16 * K, lA + 512);
        gload16(gB + k0,          lB);
        gload16(gB + k0 + 16 * K, lB + 512);
        __syncthreads();

        short8 af[4], bfr[4];
#pragma unroll
        for (int m = 0; m < 4; ++m)
            af[m] = *reinterpret_cast<const short8*>(
                &As[(wr * 64 + m * 16 + lr) * 32 + lc * 8]);
#pragma unroll
        for (int n = 0; n < 4; ++n)
            bfr[n] = *reinterpret_cast<const short8*>(
                &Bs[(wc * 64 + n * 16 + lr) * 32 + lc * 8]);
#pragma unroll
        for (int m = 0; m < 4; ++m)
#pragma unroll
            for (int n = 0; n < 4; ++n)
                acc[m][n] = __builtin_amdgcn_mfma_f32_16x16x32_bf16(
                    af[m], bfr[n], acc[m][n], 0, 0, 0);
        __syncthreads();
    }

    float bv[4];
#pragma unroll
    for (int n = 0; n < 4; ++n) bv[n] = bias[n0 + wc * 64 + n * 16 + lr];
    const int row_base = m0 + wr * 64;

    if (EPI == 0) {
        float* Cf = (float*)C;
#pragma unroll
        for (int m = 0; m < 4; ++m)
#pragma unroll
        for (int r = 0; r < 4; ++r) {
            const int row = row_base + m * 16 + lc * 4 + r;
#pragma unroll
            for (int n = 0; n < 4; ++n)
                Cf[(size_t)row * D_MODEL + n0 + wc * 64 + n * 16 + lr] =
                    acc[m][n][r] + bv[n];
        }
    } else {
        ushort* Cu = (ushort*)C;
        const bool vt = (blockIdx.z == 2);
#pragma unroll
        for (int m = 0; m < 4; ++m) {
            const int row4 = row_base + m * 16 + lc * 4;
            const int bb = row4 >> 11;
            const int ss = row4 & 2047;
            const size_t bhbase = (size_t)bb * N_HEADS;
#pragma unroll
            for (int n = 0; n < 4; ++n) {
                const int col = n0 + wc * 64 + n * 16 + lr;
                const int h = col >> 6, d = col & 63;
                if (vt) {
                    ushort4 u;
                    u.x = f2bf(acc[m][n][0] + bv[n]);
                    u.y = f2bf(acc[m][n][1] + bv[n]);
                    u.z = f2bf(acc[m][n][2] + bv[n]);
                    u.w = f2bf(acc[m][n][3] + bv[n]);
                    *reinterpret_cast<ushort4*>(
                        &Cu[((bhbase + h) * D_KK + d) * SEQ + ss]) = u;
                } else {
#pragma unroll
                    for (int r = 0; r < 4; ++r)
                        Cu[((bhbase + h) * SEQ + ss + r) * D_KK + d] =
                            f2bf(acc[m][n][r] + bv[n]);
                }
            }
        }
    }
}

// ---------------------------------------------------------------------------
// MFMA flash attention v2: LDS-staged K/V (double-buffered, pre-swizzled
// global_load_lds), XCD-aware block decode, 4 waves x 16 q-rows.
// Q,K: [bh][s][64] bf16.  Vt: [bh][64][s] bf16.  Out: [b][s][h*64+d] bf16.
// grid: flat 512 = 8 xcd * 4 bh * 16 q-pairs; block i pairs q-blocks {qx, 31-qx}.
// ---------------------------------------------------------------------------
__global__ __launch_bounds__(256)
void attn_mfma_kernel(const ushort* __restrict__ Qb, const ushort* __restrict__ Kb,
                      const ushort* __restrict__ Vt, ushort* __restrict__ Ob)
{
    __shared__ ushort Ks[2][4096];      // 64 rows x 128B, XOR-swizzled
    __shared__ ushort Vs[2][4096];
    __shared__ ushort P_lds[4][1024];   // per-wave 16x64 bf16, XOR-swizzled

    const int tid  = threadIdx.x;
    const int w    = tid >> 6;
    const int lane = tid & 63;
    const int lr   = lane & 15;
    const int lc   = lane >> 4;

    // XCD-aware decode: blocks with equal (id & 7) land on one XCD -> give
    // each XCD 4 heads (32 bh / 8 xcd) so K/V working set ~= 4 MB = L2.
    const int id  = blockIdx.x;          // 0..511
    const int xcd = id & 7;
    const int j   = id >> 3;             // 0..63
    const int bh  = xcd * 4 + (j >> 4);
    const int qx  = j & 15;
    const int b   = bh >> 4;
    const int h   = bh & 15;

    const ushort* Kbase = Kb + (size_t)bh * SEQ * D_KK;
    const ushort* Vbase = Vt + (size_t)bh * D_KK * SEQ;

    // staging geometry: tile = 8 chunks of 1KB (8 rows x 128B); wave w does
    // chunks {w, w+4} of K and of V. Source col pre-swizzled so linear LDS
    // dest ends up XOR-swizzled: colbyte = (l%8)*16 ^ (row%8)*16.
    const int rsub = lane >> 3;                    // row within chunk
    const int csw  = ((lane & 7) ^ rsub) << 3;     // element offset in row

    ushort* Pw   = &P_lds[w][0];
    const int sw_w = (lr & 7) << 4;                // frag-read XOR (byte)

    for (int half = 0; half < 2; ++half) {
        const int qb  = half ? (31 - qx) : qx;
        const int q0  = qb * 64;
        const int qr0 = q0 + w * 16;
        const int nt  = qb + 1;

        const ushort* Qp = Qb + ((size_t)bh * SEQ + qr0 + lr) * D_KK + lc * 8;
        const short8 qa0 = *reinterpret_cast<const short8*>(Qp);
        const short8 qa1 = *reinterpret_cast<const short8*>(Qp + 32);

        f32x4 acc_o[4];
        float m_run[4], l_run[4];
#pragma unroll
        for (int t = 0; t < 4; ++t) acc_o[t] = (f32x4)0.0f;
#pragma unroll
        for (int r = 0; r < 4; ++r) { m_run[r] = -1e30f; l_run[r] = 0.0f; }

        // prologue: stage tile 0 into buf 0
#pragma unroll
        for (int cc = 0; cc < 2; ++cc) {
            const int c = w + cc * 4;
            gload16(Kbase + (size_t)(c * 8 + rsub) * D_KK + csw, &Ks[0][c * 512]);
            gload16(Vbase + (size_t)(c * 8 + rsub) * SEQ + csw,  &Vs[0][c * 512]);
        }
        __syncthreads();

        int buf = 0;
        for (int it = 0; it < nt; ++it) {
            const int k0 = it * 64;
            if (it + 1 < nt) {
                const int kn = k0 + 64;
#pragma unroll
                for (int cc = 0; cc < 2; ++cc) {
                    const int c = w + cc * 4;
                    gload16(Kbase + (size_t)(kn + c * 8 + rsub) * D_KK + csw,
                            &Ks[buf ^ 1][c * 512]);
                    gload16(Vbase + (size_t)(c * 8 + rsub) * SEQ + kn + csw,
                            &Vs[buf ^ 1][c * 512]);
                }
            }
            const ushort* Ksb = &Ks[buf][0];
            const ushort* Vsb = &Vs[buf][0];

            // ---- S = Q K^T (16x64), 8 MFMA, frags from swizzled LDS ----
            f32x4 s[4];
#pragma unroll
            for (int t = 0; t < 4; ++t) {
                const int rbyte = (t * 16 + lr) * 128;
                const short8 kb0 = *reinterpret_cast<const short8*>(
                    &Ksb[(rbyte + ((lc * 16) ^ sw_w)) >> 1]);
                const short8 kb1 = *reinterpret_cast<const short8*>(
                    &Ksb[(rbyte + ((64 + lc * 16) ^ sw_w)) >> 1]);
                f32x4 a = (f32x4)0.0f;
                a = __builtin_amdgcn_mfma_f32_16x16x32_bf16(qa0, kb0, a, 0, 0, 0);
                a = __builtin_amdgcn_mfma_f32_16x16x32_bf16(qa1, kb1, a, 0, 0, 0);
                s[t] = a;
            }

            // ---- scale + causal mask + online softmax ----
            const bool needmask = (k0 + 63 > qr0);
            float mx[4], rs[4];
#pragma unroll
            for (int r = 0; r < 4; ++r) {
                const int qrow = qr0 + lc * 4 + r;
                float best = -1e30f;
#pragma unroll
                for (int t = 0; t < 4; ++t) {
                    float v = s[t][r] * 0.125f;
                    if (needmask && (k0 + t * 16 + lr > qrow)) v = -1e30f;
                    s[t][r] = v;
                    best = fmaxf(best, v);
                }
                mx[r] = best;
            }
#pragma unroll
            for (int off = 1; off < 16; off <<= 1)
#pragma unroll
                for (int r = 0; r < 4; ++r)
                    mx[r] = fmaxf(mx[r], __shfl_xor(mx[r], off));

#pragma unroll
            for (int r = 0; r < 4; ++r) {
                const float mn   = fmaxf(m_run[r], mx[r]);
                const float corr = __expf(m_run[r] - mn);
                m_run[r] = mn;
                l_run[r] *= corr;
                acc_o[0][r] *= corr; acc_o[1][r] *= corr;
                acc_o[2][r] *= corr; acc_o[3][r] *= corr;
                float sum = 0.0f;
#pragma unroll
                for (int t = 0; t < 4; ++t) {
                    float p = __expf(s[t][r] - mn);
                    s[t][r] = p;
                    sum += p;
                }
                rs[r] = sum;
            }
#pragma unroll
            for (int off = 1; off < 16; off <<= 1)
#pragma unroll
                for (int r = 0; r < 4; ++r)
                    rs[r] += __shfl_xor(rs[r], off);
#pragma unroll
            for (int r = 0; r < 4; ++r) l_run[r] += rs[r];

            // ---- P -> per-wave LDS (bf16, swizzled) ----
#pragma unroll
            for (int r = 0; r < 4; ++r) {
                const int row = lc * 4 + r;
                const int sw  = (row & 7) << 4;
#pragma unroll
                for (int t = 0; t < 4; ++t) {
                    const int byte = row * 128 + ((((t * 16 + lr) * 2)) ^ sw);
                    Pw[byte >> 1] = f2bf(s[t][r]);
                }
            }
            const short8 pa0 = *reinterpret_cast<const short8*>(
                &Pw[(lr * 128 + ((lc * 16) ^ sw_w)) >> 1]);
            const short8 pa1 = *reinterpret_cast<const short8*>(
                &Pw[(lr * 128 + ((64 + lc * 16) ^ sw_w)) >> 1]);

            // ---- O += P V (16x64), 8 MFMA, V frags from swizzled LDS ----
#pragma unroll
            for (int t = 0; t < 4; ++t) {
                const int rbyte = (t * 16 + lr) * 128;
                const short8 vb0 = *reinterpret_cast<const short8*>(
                    &Vsb[(rbyte + ((lc * 16) ^ sw_w)) >> 1]);
                const short8 vb1 = *reinterpret_cast<const short8*>(
                    &Vsb[(rbyte + ((64 + lc * 16) ^ sw_w)) >> 1]);
                acc_o[t] = __builtin_amdgcn_mfma_f32_16x16x32_bf16(
                        pa0, vb0, acc_o[t], 0, 0, 0);
                acc_o[t] = __builtin_amdgcn_mfma_f32_16x16x32_bf16(
                        pa1, vb1, acc_o[t], 0, 0, 0);
            }

            __syncthreads();
            buf ^= 1;
        }

        // ---- normalize + store (bf16) ----
#pragma unroll
        for (int r = 0; r < 4; ++r) {
            const float inv  = 1.0f / l_run[r];
            const int   qrow = qr0 + lc * 4 + r;
            ushort* Op = Ob + ((size_t)b * SEQ + qrow) * D_MODEL + h * D_KK;
#pragma unroll
            for (int t = 0; t < 4; ++t)
                Op[t * 16 + lr] = f2bf(acc_o[t][r] * inv);
        }
    }
}

// ---------------------------------------------------------------------------
extern "C" void kernel_launch(void* const* d_in, const int* in_sizes, int n_in,
                              void* d_out, int out_size, void* d_ws, size_t ws_size,
                              hipStream_t stream)
{
    const float* x  = (const float*)d_in[0];
    const float* Wq = (const float*)d_in[2];
    const float* bq = (const float*)d_in[3];
    const float* Wk = (const float*)d_in[4];
    const float* bk = (const float*)d_in[5];
    const float* Wv = (const float*)d_in[6];
    const float* bv = (const float*)d_in[7];
    const float* Wo = (const float*)d_in[8];
    const float* bo = (const float*)d_in[9];
    float* out = (float*)d_out;

    const size_t TSZ = (size_t)M_TOTAL * D_MODEL;
    const size_t WSZ = (size_t)D_MODEL * D_MODEL;
    ushort* xb  = (ushort*)d_ws;
    ushort* Wqb = xb  + TSZ;
    ushort* Wkb = Wqb + WSZ;
    ushort* Wvb = Wkb + WSZ;
    ushort* Wob = Wvb + WSZ;
    ushort* Qb  = Wob + WSZ;
    ushort* Kb  = Qb  + TSZ;
    ushort* Vt  = Kb  + TSZ;
    ushort* Ob  = Vt  + TSZ;

    dim3 blk(256);
    cvt_kernel<<<dim3(256, 5), blk, 0, stream>>>(x, Wq, Wk, Wv, Wo,
                                                 xb, Wqb, Wkb, Wvb, Wob);

    dim3 g_qkv(M_TOTAL / 128, D_MODEL / 128, 3);
    gemm_mfma<1><<<g_qkv, blk, 0, stream>>>(xb, Wqb, bq, Qb,
                                                Wkb, bk, Kb,
                                                Wvb, bv, Vt);

    attn_mfma_kernel<<<dim3(512), blk, 0, stream>>>(Qb, Kb, Vt, Ob);

    dim3 g_o(M_TOTAL / 128, D_MODEL / 128, 1);
    gemm_mfma<0><<<g_o, blk, 0, stream>>>(Ob, Wob, bo, out, Wob, bo, out, Wob, bo, out);
}

// Round 5
// 123.588 us; speedup vs baseline: 15.8574x; 1.2446x over previous
//
#include <hip/hip_runtime.h>
#include <math.h>
#include <type_traits>

#define D_MODEL 1024
#define N_HEADS 16
#define D_KK    64
#define B_SZ    2
#define SEQ     2048
#define M_TOTAL (B_SZ * SEQ)   // 4096

// 0.125 * log2(e): folds attention scale AND exp->exp2 conversion into Q
#define QSCALE 0.18033688011112042f

typedef __attribute__((ext_vector_type(8))) short short8;
typedef __attribute__((ext_vector_type(4))) float f32x4;

static __device__ __forceinline__ ushort f2bf(float f) {
    union { float f; unsigned u; } c; c.f = f;
    unsigned u = c.u;
    unsigned r = (u + 0x7fffu + ((u >> 16) & 1u)) >> 16;   // RNE
    return (ushort)r;
}

// pack two f32 -> two bf16 in one u32 (round-half-up + v_perm_b32)
static __device__ __forceinline__ unsigned packbf(float a, float b) {
    unsigned ua = __float_as_uint(a) + 0x8000u;
    unsigned ub = __float_as_uint(b) + 0x8000u;
    return __builtin_amdgcn_perm(ub, ua, 0x07060302u);  // [b.hi16 : a.hi16]
}

static __device__ __forceinline__ void gload16(const void* g, void* l) {
    __builtin_amdgcn_global_load_lds(
        (const __attribute__((address_space(1))) void*)g,
        (__attribute__((address_space(3))) void*)l, 16, 0, 0);
}

// ---------------------------------------------------------------------------
// fp32 -> bf16 conversion: x and the four weight matrices.
// ---------------------------------------------------------------------------
__global__ __launch_bounds__(256)
void cvt_kernel(const float* __restrict__ x,  const float* __restrict__ wq,
                const float* __restrict__ wk, const float* __restrict__ wv,
                const float* __restrict__ wo,
                ushort* __restrict__ xb,  ushort* __restrict__ wqb,
                ushort* __restrict__ wkb, ushort* __restrict__ wvb,
                ushort* __restrict__ wob)
{
    const float* s; ushort* d; int n4;
    switch (blockIdx.y) {
        case 0:  s = x;  d = xb;  n4 = M_TOTAL * D_MODEL / 4; break;
        case 1:  s = wq; d = wqb; n4 = D_MODEL * D_MODEL / 4; break;
        case 2:  s = wk; d = wkb; n4 = D_MODEL * D_MODEL / 4; break;
        case 3:  s = wv; d = wvb; n4 = D_MODEL * D_MODEL / 4; break;
        default: s = wo; d = wob; n4 = D_MODEL * D_MODEL / 4; break;
    }
    const int stride = gridDim.x * blockDim.x;
    for (int i = blockIdx.x * blockDim.x + threadIdx.x; i < n4; i += stride) {
        float4 v = reinterpret_cast<const float4*>(s)[i];
        ushort4 u;
        u.x = f2bf(v.x); u.y = f2bf(v.y); u.z = f2bf(v.z); u.w = f2bf(v.w);
        reinterpret_cast<ushort4*>(d)[i] = u;
    }
}

// ---------------------------------------------------------------------------
// bf16 MFMA GEMM (m97 structure): C[m,n] = sum_k A[m,k]*W[n,k] + bias[n]
// EPI=1, z==0 additionally scales Q output by QSCALE (softmax fold).
// ---------------------------------------------------------------------------
template<int EPI>
__global__ __launch_bounds__(256)
void gemm_mfma(const ushort* __restrict__ A,
               const ushort* __restrict__ W0, const float* __restrict__ b0, void* __restrict__ C0,
               const ushort* __restrict__ W1, const float* __restrict__ b1, void* __restrict__ C1,
               const ushort* __restrict__ W2, const float* __restrict__ b2, void* __restrict__ C2)
{
    constexpr int K = D_MODEL;

    const ushort* W    = W0;
    const float*  bias = b0;
    void*         C    = C0;
    if (blockIdx.z == 1) { W = W1; bias = b1; C = C1; }
    else if (blockIdx.z == 2) { W = W2; bias = b2; C = C2; }

    __shared__ ushort As[128 * 32];
    __shared__ ushort Bs[128 * 32];

    const int tid  = threadIdx.x;
    const int w    = tid >> 6;
    const int lane = tid & 63;
    const int lr   = lane & 15;
    const int lc   = lane >> 4;
    const int wr   = w >> 1;
    const int wc   = w & 1;
    const int m0   = blockIdx.x * 128;
    const int n0   = blockIdx.y * 128;

    const int srow = lane >> 2;
    const int scol = (lane & 3) * 8;
    const int g0   = w * 2;

    const ushort* gA = A + (size_t)(m0 + g0 * 16 + srow) * K + scol;
    const ushort* gB = W + (size_t)(n0 + g0 * 16 + srow) * K + scol;
    ushort* lA = &As[g0 * 512];
    ushort* lB = &Bs[g0 * 512];

    f32x4 acc[4][4];
#pragma unroll
    for (int m = 0; m < 4; ++m)
#pragma unroll
        for (int n = 0; n < 4; ++n) acc[m][n] = (f32x4)0.0f;

    for (int k0 = 0; k0 < K; k0 += 32) {
        gload16(gA + k0,          lA);
        gload16(gA + k0 + 16 * K, lA + 512);
        gload16(gB + k0,          lB);
        gload16(gB + k0 + 16 * K, lB + 512);
        __syncthreads();

        short8 af[4], bfr[4];
#pragma unroll
        for (int m = 0; m < 4; ++m)
            af[m] = *reinterpret_cast<const short8*>(
                &As[(wr * 64 + m * 16 + lr) * 32 + lc * 8]);
#pragma unroll
        for (int n = 0; n < 4; ++n)
            bfr[n] = *reinterpret_cast<const short8*>(
                &Bs[(wc * 64 + n * 16 + lr) * 32 + lc * 8]);
#pragma unroll
        for (int m = 0; m < 4; ++m)
#pragma unroll
            for (int n = 0; n < 4; ++n)
                acc[m][n] = __builtin_amdgcn_mfma_f32_16x16x32_bf16(
                    af[m], bfr[n], acc[m][n], 0, 0, 0);
        __syncthreads();
    }

    float bv[4];
#pragma unroll
    for (int n = 0; n < 4; ++n) bv[n] = bias[n0 + wc * 64 + n * 16 + lr];
    const int row_base = m0 + wr * 64;

    if (EPI == 0) {
        float* Cf = (float*)C;
#pragma unroll
        for (int m = 0; m < 4; ++m)
#pragma unroll
        for (int r = 0; r < 4; ++r) {
            const int row = row_base + m * 16 + lc * 4 + r;
#pragma unroll
            for (int n = 0; n < 4; ++n)
                Cf[(size_t)row * D_MODEL + n0 + wc * 64 + n * 16 + lr] =
                    acc[m][n][r] + bv[n];
        }
    } else {
        ushort* Cu = (ushort*)C;
        const bool vt  = (blockIdx.z == 2);
        const float osc = (blockIdx.z == 0) ? QSCALE : 1.0f;
#pragma unroll
        for (int m = 0; m < 4; ++m) {
            const int row4 = row_base + m * 16 + lc * 4;
            const int bb = row4 >> 11;
            const int ss = row4 & 2047;
            const size_t bhbase = (size_t)bb * N_HEADS;
#pragma unroll
            for (int n = 0; n < 4; ++n) {
                const int col = n0 + wc * 64 + n * 16 + lr;
                const int h = col >> 6, d = col & 63;
                if (vt) {
                    ushort4 u;
                    u.x = f2bf(acc[m][n][0] + bv[n]);
                    u.y = f2bf(acc[m][n][1] + bv[n]);
                    u.z = f2bf(acc[m][n][2] + bv[n]);
                    u.w = f2bf(acc[m][n][3] + bv[n]);
                    *reinterpret_cast<ushort4*>(
                        &Cu[((bhbase + h) * D_KK + d) * SEQ + ss]) = u;
                } else {
#pragma unroll
                    for (int r = 0; r < 4; ++r)
                        Cu[((bhbase + h) * SEQ + ss + r) * D_KK + d] =
                            f2bf((acc[m][n][r] + bv[n]) * osc);
                }
            }
        }
    }
}

// ---------------------------------------------------------------------------
// MFMA flash attention v3: swapped QK^T (S^T layout, per-lane softmax row),
// exp2 domain (scale folded into Q), defer-max, peeled diagonal tile,
// LDS-staged double-buffered K/V, 1024 blocks (4/CU).
// Q,K: [bh][s][64] bf16 (Q pre-scaled).  Vt: [bh][64][s] bf16.
// Out: [b][s][h*64+d] bf16.
// ---------------------------------------------------------------------------
__global__ __launch_bounds__(256, 4)
void attn_mfma_kernel(const ushort* __restrict__ Qb, const ushort* __restrict__ Kb,
                      const ushort* __restrict__ Vt, ushort* __restrict__ Ob)
{
    __shared__ ushort Ks[2][4096];      // 64 rows x 128B, XOR-swizzled
    __shared__ ushort Vs[2][4096];
    __shared__ ushort P_lds[4][1024];   // per-wave 16x64 bf16, XOR-swizzled

    const int tid  = threadIdx.x;
    const int w    = tid >> 6;
    const int lane = tid & 63;
    const int lr   = lane & 15;
    const int lc   = lane >> 4;

    // decode: 1024 = 8 xcd * 4 bh * 32 qb; qb descending so big blocks start first
    const int id  = blockIdx.x;
    const int xcd = id & 7;
    const int j   = id >> 3;             // 0..127
    const int bh  = xcd * 4 + (j & 3);
    const int qb  = 31 - (j >> 2);
    const int b   = bh >> 4;
    const int h   = bh & 15;
    const int q0  = qb * 64;
    const int qr0 = q0 + w * 16;
    const int nt  = qb + 1;

    const ushort* Kbase = Kb + (size_t)bh * SEQ * D_KK;
    const ushort* Vbase = Vt + (size_t)bh * D_KK * SEQ;

    // staging: 8 chunks of 1KB (8 rows x 128B); wave w does chunks {w, w+4}.
    // source col pre-swizzled -> linear LDS dest lands XOR-swizzled.
    const int rsub = lane >> 3;
    const int csw  = ((lane & 7) ^ rsub) << 3;

    ushort* Pw     = &P_lds[w][0];
    const int sw_w = (lr & 7) << 4;      // row-XOR for LDS reads/writes (bytes)

    // Q frags (A-of-QK^T becomes B now; same layout either way)
    const ushort* Qp = Qb + ((size_t)bh * SEQ + qr0 + lr) * D_KK + lc * 8;
    const short8 qa0 = *reinterpret_cast<const short8*>(Qp);
    const short8 qa1 = *reinterpret_cast<const short8*>(Qp + 32);

    f32x4 acc_o[4];
#pragma unroll
    for (int t = 0; t < 4; ++t) acc_o[t] = (f32x4)0.0f;
    float m_run = -1e30f;                // per-lane row (q = lr), dup across lc
    float l_run = 0.0f;

    // prologue: stage tile 0 -> buf 0
#pragma unroll
    for (int cc = 0; cc < 2; ++cc) {
        const int c = w + cc * 4;
        gload16(Kbase + (size_t)(c * 8 + rsub) * D_KK + csw, &Ks[0][c * 512]);
        gload16(Vbase + (size_t)(c * 8 + rsub) * SEQ + csw,  &Vs[0][c * 512]);
    }
    __syncthreads();

    auto tile_body = [&](int buf, auto maskc) {
        constexpr bool MASK = decltype(maskc)::value;
        const ushort* Ksb = &Ks[buf][0];
        const ushort* Vsb = &Vs[buf][0];

        // ---- S^T = K Q^T : lane holds q=lr, k = t*16 + lc*4 + r ----
        f32x4 s[4];
#pragma unroll
        for (int t = 0; t < 4; ++t) {
            const int rbyte = (t * 16 + lr) * 128;
            const short8 kb0 = *reinterpret_cast<const short8*>(
                &Ksb[(rbyte + ((lc * 16) ^ sw_w)) >> 1]);
            const short8 kb1 = *reinterpret_cast<const short8*>(
                &Ksb[(rbyte + ((64 + lc * 16) ^ sw_w)) >> 1]);
            f32x4 a = (f32x4)0.0f;
            a = __builtin_amdgcn_mfma_f32_16x16x32_bf16(kb0, qa0, a, 0, 0, 0);
            a = __builtin_amdgcn_mfma_f32_16x16x32_bf16(kb1, qa1, a, 0, 0, 0);
            s[t] = a;
        }

        // ---- mask (diagonal tile only) + in-lane max ----
        float tmax = -1e30f;
#pragma unroll
        for (int t = 0; t < 4; ++t)
#pragma unroll
            for (int r = 0; r < 4; ++r) {
                if (MASK) {
                    const int kl = t * 16 + lc * 4 + r;      // k0 == q0 here
                    if (kl > w * 16 + lr) s[t][r] = -1e30f;
                }
                tmax = fmaxf(tmax, s[t][r]);
            }
        tmax = fmaxf(tmax, __shfl_xor(tmax, 16));
        tmax = fmaxf(tmax, __shfl_xor(tmax, 32));

        // ---- defer-max rescale (rare) ----
        if (!__all(tmax <= m_run + 8.0f)) {
            const float mnew = fmaxf(m_run, tmax);
            const float corr = __builtin_amdgcn_exp2f(m_run - mnew);
            m_run = mnew;
            l_run *= corr;
            float cr[4];
#pragma unroll
            for (int r = 0; r < 4; ++r) cr[r] = __shfl(corr, lc * 4 + r, 16);
#pragma unroll
            for (int t = 0; t < 4; ++t)
#pragma unroll
                for (int r = 0; r < 4; ++r) acc_o[t][r] *= cr[r];
        }

        // ---- p = exp2(s - m); row-sum; pack -> LDS (b64 per t) ----
        float rsum = 0.0f;
#pragma unroll
        for (int t = 0; t < 4; ++t) {
#pragma unroll
            for (int r = 0; r < 4; ++r) {
                const float p = __builtin_amdgcn_exp2f(s[t][r] - m_run);
                s[t][r] = p;
                rsum += p;
            }
            const unsigned lo = packbf(s[t][0], s[t][1]);
            const unsigned hi = packbf(s[t][2], s[t][3]);
            *reinterpret_cast<uint2*>(
                &Pw[(lr * 128 + ((t * 32 + lc * 8) ^ sw_w)) >> 1]) =
                make_uint2(lo, hi);
        }
        rsum += __shfl_xor(rsum, 16);
        rsum += __shfl_xor(rsum, 32);
        l_run += rsum;

        // ---- PA frags from own wave's LDS region ----
        const short8 pa0 = *reinterpret_cast<const short8*>(
            &Pw[(lr * 128 + ((lc * 16) ^ sw_w)) >> 1]);
        const short8 pa1 = *reinterpret_cast<const short8*>(
            &Pw[(lr * 128 + ((64 + lc * 16) ^ sw_w)) >> 1]);

        // ---- O += P V ----
#pragma unroll
        for (int t = 0; t < 4; ++t) {
            const int rbyte = (t * 16 + lr) * 128;
            const short8 vb0 = *reinterpret_cast<const short8*>(
                &Vsb[(rbyte + ((lc * 16) ^ sw_w)) >> 1]);
            const short8 vb1 = *reinterpret_cast<const short8*>(
                &Vsb[(rbyte + ((64 + lc * 16) ^ sw_w)) >> 1]);
            acc_o[t] = __builtin_amdgcn_mfma_f32_16x16x32_bf16(
                    pa0, vb0, acc_o[t], 0, 0, 0);
            acc_o[t] = __builtin_amdgcn_mfma_f32_16x16x32_bf16(
                    pa1, vb1, acc_o[t], 0, 0, 0);
        }
    };

    int buf = 0;
    for (int it = 0; it < nt - 1; ++it) {
        const int kn = (it + 1) * 64;          // prefetch next tile -> buf^1
#pragma unroll
        for (int cc = 0; cc < 2; ++cc) {
            const int c = w + cc * 4;
            gload16(Kbase + (size_t)(kn + c * 8 + rsub) * D_KK + csw,
                    &Ks[buf ^ 1][c * 512]);
            gload16(Vbase + (size_t)(c * 8 + rsub) * SEQ + kn + csw,
                    &Vs[buf ^ 1][c * 512]);
        }
        tile_body(buf, std::integral_constant<bool, false>{});
        __syncthreads();
        buf ^= 1;
    }
    tile_body(buf, std::integral_constant<bool, true>{});   // diagonal tile

    // ---- normalize + store ----
    const float linv = 1.0f / l_run;
    float invr[4];
#pragma unroll
    for (int r = 0; r < 4; ++r) invr[r] = __shfl(linv, lc * 4 + r, 16);
#pragma unroll
    for (int r = 0; r < 4; ++r) {
        const int qrow = qr0 + lc * 4 + r;
        ushort* Op = Ob + ((size_t)b * SEQ + qrow) * D_MODEL + h * D_KK;
#pragma unroll
        for (int t = 0; t < 4; ++t)
            Op[t * 16 + lr] = f2bf(acc_o[t][r] * invr[r]);
    }
}

// ---------------------------------------------------------------------------
extern "C" void kernel_launch(void* const* d_in, const int* in_sizes, int n_in,
                              void* d_out, int out_size, void* d_ws, size_t ws_size,
                              hipStream_t stream)
{
    const float* x  = (const float*)d_in[0];
    const float* Wq = (const float*)d_in[2];
    const float* bq = (const float*)d_in[3];
    const float* Wk = (const float*)d_in[4];
    const float* bk = (const float*)d_in[5];
    const float* Wv = (const float*)d_in[6];
    const float* bv = (const float*)d_in[7];
    const float* Wo = (const float*)d_in[8];
    const float* bo = (const float*)d_in[9];
    float* out = (float*)d_out;

    const size_t TSZ = (size_t)M_TOTAL * D_MODEL;
    const size_t WSZ = (size_t)D_MODEL * D_MODEL;
    ushort* xb  = (ushort*)d_ws;
    ushort* Wqb = xb  + TSZ;
    ushort* Wkb = Wqb + WSZ;
    ushort* Wvb = Wkb + WSZ;
    ushort* Wob = Wvb + WSZ;
    ushort* Qb  = Wob + WSZ;
    ushort* Kb  = Qb  + TSZ;
    ushort* Vt  = Kb  + TSZ;
    ushort* Ob  = Vt  + TSZ;

    dim3 blk(256);
    cvt_kernel<<<dim3(256, 5), blk, 0, stream>>>(x, Wq, Wk, Wv, Wo,
                                                 xb, Wqb, Wkb, Wvb, Wob);

    dim3 g_qkv(M_TOTAL / 128, D_MODEL / 128, 3);
    gemm_mfma<1><<<g_qkv, blk, 0, stream>>>(xb, Wqb, bq, Qb,
                                                Wkb, bk, Kb,
                                                Wvb, bv, Vt);

    attn_mfma_kernel<<<dim3(1024), blk, 0, stream>>>(Qb, Kb, Vt, Ob);

    dim3 g_o(M_TOTAL / 128, D_MODEL / 128, 1);
    gemm_mfma<0><<<g_o, blk, 0, stream>>>(Ob, Wob, bo, out, Wob, bo, out, Wob, bo, out);
}

// Round 6
// 106.343 us; speedup vs baseline: 18.4290x; 1.1622x over previous
//
#include <hip/hip_runtime.h>
#include <math.h>
#include <type_traits>

#define D_MODEL 1024
#define N_HEADS 16
#define D_KK    64
#define B_SZ    2
#define SEQ     2048
#define M_TOTAL (B_SZ * SEQ)   // 4096

// 0.125 * log2(e): folds attention scale AND exp->exp2 conversion into Q
#define QSCALE 0.18033688011112042f

typedef __attribute__((ext_vector_type(8))) short short8;
typedef __attribute__((ext_vector_type(4))) float f32x4;

static __device__ __forceinline__ ushort f2bf(float f) {
    union { float f; unsigned u; } c; c.f = f;
    unsigned u = c.u;
    unsigned r = (u + 0x7fffu + ((u >> 16) & 1u)) >> 16;   // RNE
    return (ushort)r;
}

// pack two f32 -> two bf16 in one u32 (round-half-up + v_perm_b32)
static __device__ __forceinline__ unsigned packbf(float a, float b) {
    unsigned ua = __float_as_uint(a) + 0x8000u;
    unsigned ub = __float_as_uint(b) + 0x8000u;
    return __builtin_amdgcn_perm(ub, ua, 0x07060302u);
}

static __device__ __forceinline__ void gload16(const void* g, void* l) {
    __builtin_amdgcn_global_load_lds(
        (const __attribute__((address_space(1))) void*)g,
        (__attribute__((address_space(3))) void*)l, 16, 0, 0);
}

// ---------------------------------------------------------------------------
// fp32 -> bf16 conversion: x and the four weight matrices.
// ---------------------------------------------------------------------------
__global__ __launch_bounds__(256)
void cvt_kernel(const float* __restrict__ x,  const float* __restrict__ wq,
                const float* __restrict__ wk, const float* __restrict__ wv,
                const float* __restrict__ wo,
                ushort* __restrict__ xb,  ushort* __restrict__ wqb,
                ushort* __restrict__ wkb, ushort* __restrict__ wvb,
                ushort* __restrict__ wob)
{
    const float* s; ushort* d; int n4;
    switch (blockIdx.y) {
        case 0:  s = x;  d = xb;  n4 = M_TOTAL * D_MODEL / 4; break;
        case 1:  s = wq; d = wqb; n4 = D_MODEL * D_MODEL / 4; break;
        case 2:  s = wk; d = wkb; n4 = D_MODEL * D_MODEL / 4; break;
        case 3:  s = wv; d = wvb; n4 = D_MODEL * D_MODEL / 4; break;
        default: s = wo; d = wob; n4 = D_MODEL * D_MODEL / 4; break;
    }
    const int stride = gridDim.x * blockDim.x;
    for (int i = blockIdx.x * blockDim.x + threadIdx.x; i < n4; i += stride) {
        float4 v = reinterpret_cast<const float4*>(s)[i];
        ushort4 u;
        u.x = f2bf(v.x); u.y = f2bf(v.y); u.z = f2bf(v.z); u.w = f2bf(v.w);
        reinterpret_cast<ushort4*>(d)[i] = u;
    }
}

// ---------------------------------------------------------------------------
// bf16 MFMA GEMM v2: C[m,n] = sum_k A[m,k]*W[n,k] + bias[n]
// BM=128 BN=64 BK=64, 4 waves (2x2: wave = 64m x 32n), dbuf prefetch,
// pre-swizzled global_load_lds (conflict-free ds_read_b128, same geometry as
// the attention kernel). Flat grid, XCD-chunked decode:
//   xcd=id&7, j=id>>3: mt=xcd*4+(j&3), nt=(j>>2)&15, z=(j>>2)>>4.
// EPI=0: fp32 C[m][N].  EPI=1: z=0,1 -> bf16 [bh][s][64] (z=0 *QSCALE);
//                        z=2 -> bf16 V^T [bh][64][s].
// ---------------------------------------------------------------------------
template<int EPI>
__global__ __launch_bounds__(256)
void gemm_mfma(const ushort* __restrict__ A,
               const ushort* __restrict__ W0, const float* __restrict__ b0, void* __restrict__ C0,
               const ushort* __restrict__ W1, const float* __restrict__ b1, void* __restrict__ C1,
               const ushort* __restrict__ W2, const float* __restrict__ b2, void* __restrict__ C2)
{
    constexpr int K = D_MODEL;

    __shared__ ushort As[2][128 * 64];   // 32 KB
    __shared__ ushort Bs[2][64 * 64];    // 16 KB

    const int id  = blockIdx.x;
    const int xcd = id & 7;
    const int j   = id >> 3;
    const int mt  = xcd * 4 + (j & 3);
    const int ntz = j >> 2;
    const int nt  = ntz & 15;
    const int z   = ntz >> 4;

    const ushort* W    = W0;
    const float*  bias = b0;
    void*         C    = C0;
    if (z == 1) { W = W1; bias = b1; C = C1; }
    else if (z == 2) { W = W2; bias = b2; C = C2; }

    const int m0 = mt * 128;
    const int n0 = nt * 64;

    const int tid  = threadIdx.x;
    const int w    = tid >> 6;
    const int lane = tid & 63;
    const int lr   = lane & 15;
    const int lc   = lane >> 4;
    const int wr   = w >> 1;
    const int wc   = w & 1;

    // staging: chunk = 8 rows x 128B; A has 16 chunks, B has 8.
    // wave w stages A chunks {w,w+4,w+8,w+12}, B chunks {w,w+4}.
    // source col pre-swizzled so linear LDS dest lands XOR-swizzled.
    const int rsub = lane >> 3;                    // row in chunk
    const int csw  = ((lane & 7) ^ rsub) << 3;     // element offset in row

    const ushort* gA = A + (size_t)(m0 + w * 8 + rsub) * K + csw;
    const ushort* gB = W + (size_t)(n0 + w * 8 + rsub) * K + csw;

    f32x4 acc[4][2];
#pragma unroll
    for (int m = 0; m < 4; ++m)
#pragma unroll
        for (int n = 0; n < 2; ++n) acc[m][n] = (f32x4)0.0f;

    // prologue: stage k-tile 0 -> buf 0
#pragma unroll
    for (int ca = 0; ca < 4; ++ca)
        gload16(gA + (size_t)(32 * ca) * K, &As[0][(w + 4 * ca) * 512]);
#pragma unroll
    for (int cb = 0; cb < 2; ++cb)
        gload16(gB + (size_t)(32 * cb) * K, &Bs[0][(w + 4 * cb) * 512]);
    __syncthreads();

    const int swz = (lr & 7) << 4;                 // frag-read XOR (bytes)
    int buf = 0;
    for (int it = 0; it < 16; ++it) {
        if (it < 15) {
            const int kn = (it + 1) * 64;
#pragma unroll
            for (int ca = 0; ca < 4; ++ca)
                gload16(gA + (size_t)(32 * ca) * K + kn, &As[buf ^ 1][(w + 4 * ca) * 512]);
#pragma unroll
            for (int cb = 0; cb < 2; ++cb)
                gload16(gB + (size_t)(32 * cb) * K + kn, &Bs[buf ^ 1][(w + 4 * cb) * 512]);
        }

        short8 af[4][2], bfr[2][2];
#pragma unroll
        for (int m = 0; m < 4; ++m) {
            const int rbyte = (wr * 64 + m * 16 + lr) * 128;
#pragma unroll
            for (int kk = 0; kk < 2; ++kk)
                af[m][kk] = *reinterpret_cast<const short8*>(
                    &As[buf][(rbyte + ((kk * 64 + lc * 16) ^ swz)) >> 1]);
        }
#pragma unroll
        for (int n = 0; n < 2; ++n) {
            const int rbyte = (wc * 32 + n * 16 + lr) * 128;
#pragma unroll
            for (int kk = 0; kk < 2; ++kk)
                bfr[n][kk] = *reinterpret_cast<const short8*>(
                    &Bs[buf][(rbyte + ((kk * 64 + lc * 16) ^ swz)) >> 1]);
        }
#pragma unroll
        for (int kk = 0; kk < 2; ++kk)
#pragma unroll
            for (int m = 0; m < 4; ++m)
#pragma unroll
                for (int n = 0; n < 2; ++n)
                    acc[m][n] = __builtin_amdgcn_mfma_f32_16x16x32_bf16(
                        af[m][kk], bfr[n][kk], acc[m][n], 0, 0, 0);

        __syncthreads();
        buf ^= 1;
    }

    // epilogue: row = m0+wr*64+m*16+lc*4+r ; col = n0+wc*32+n*16+lr
    float bv[2];
#pragma unroll
    for (int n = 0; n < 2; ++n) bv[n] = bias[n0 + wc * 32 + n * 16 + lr];
    const int row_base = m0 + wr * 64;

    if (EPI == 0) {
        float* Cf = (float*)C;
#pragma unroll
        for (int m = 0; m < 4; ++m)
#pragma unroll
        for (int r = 0; r < 4; ++r) {
            const int row = row_base + m * 16 + lc * 4 + r;
#pragma unroll
            for (int n = 0; n < 2; ++n)
                Cf[(size_t)row * D_MODEL + n0 + wc * 32 + n * 16 + lr] =
                    acc[m][n][r] + bv[n];
        }
    } else {
        ushort* Cu = (ushort*)C;
        const bool vt   = (z == 2);
        const float osc = (z == 0) ? QSCALE : 1.0f;
#pragma unroll
        for (int m = 0; m < 4; ++m) {
            const int row4 = row_base + m * 16 + lc * 4;
            const int bb = row4 >> 11;
            const int ss = row4 & 2047;
            const size_t bhbase = (size_t)bb * N_HEADS;
#pragma unroll
            for (int n = 0; n < 2; ++n) {
                const int col = n0 + wc * 32 + n * 16 + lr;
                const int h = col >> 6, d = col & 63;
                if (vt) {
                    ushort4 u;
                    u.x = f2bf(acc[m][n][0] + bv[n]);
                    u.y = f2bf(acc[m][n][1] + bv[n]);
                    u.z = f2bf(acc[m][n][2] + bv[n]);
                    u.w = f2bf(acc[m][n][3] + bv[n]);
                    *reinterpret_cast<ushort4*>(
                        &Cu[((bhbase + h) * D_KK + d) * SEQ + ss]) = u;
                } else {
#pragma unroll
                    for (int r = 0; r < 4; ++r)
                        Cu[((bhbase + h) * SEQ + ss + r) * D_KK + d] =
                            f2bf((acc[m][n][r] + bv[n]) * osc);
                }
            }
        }
    }
}

// ---------------------------------------------------------------------------
// MFMA flash attention v3 (unchanged from round 5): swapped QK^T, exp2 domain,
// defer-max, peeled diagonal, LDS-staged dbuf K/V, 1024 blocks.
// ---------------------------------------------------------------------------
__global__ __launch_bounds__(256, 4)
void attn_mfma_kernel(const ushort* __restrict__ Qb, const ushort* __restrict__ Kb,
                      const ushort* __restrict__ Vt, ushort* __restrict__ Ob)
{
    __shared__ ushort Ks[2][4096];
    __shared__ ushort Vs[2][4096];
    __shared__ ushort P_lds[4][1024];

    const int tid  = threadIdx.x;
    const int w    = tid >> 6;
    const int lane = tid & 63;
    const int lr   = lane & 15;
    const int lc   = lane >> 4;

    const int id  = blockIdx.x;
    const int xcd = id & 7;
    const int j   = id >> 3;
    const int bh  = xcd * 4 + (j & 3);
    const int qb  = 31 - (j >> 2);
    const int b   = bh >> 4;
    const int h   = bh & 15;
    const int q0  = qb * 64;
    const int qr0 = q0 + w * 16;
    const int nt  = qb + 1;

    const ushort* Kbase = Kb + (size_t)bh * SEQ * D_KK;
    const ushort* Vbase = Vt + (size_t)bh * D_KK * SEQ;

    const int rsub = lane >> 3;
    const int csw  = ((lane & 7) ^ rsub) << 3;

    ushort* Pw     = &P_lds[w][0];
    const int sw_w = (lr & 7) << 4;

    const ushort* Qp = Qb + ((size_t)bh * SEQ + qr0 + lr) * D_KK + lc * 8;
    const short8 qa0 = *reinterpret_cast<const short8*>(Qp);
    const short8 qa1 = *reinterpret_cast<const short8*>(Qp + 32);

    f32x4 acc_o[4];
#pragma unroll
    for (int t = 0; t < 4; ++t) acc_o[t] = (f32x4)0.0f;
    float m_run = -1e30f;
    float l_run = 0.0f;

#pragma unroll
    for (int cc = 0; cc < 2; ++cc) {
        const int c = w + cc * 4;
        gload16(Kbase + (size_t)(c * 8 + rsub) * D_KK + csw, &Ks[0][c * 512]);
        gload16(Vbase + (size_t)(c * 8 + rsub) * SEQ + csw,  &Vs[0][c * 512]);
    }
    __syncthreads();

    auto tile_body = [&](int buf, auto maskc) {
        constexpr bool MASK = decltype(maskc)::value;
        const ushort* Ksb = &Ks[buf][0];
        const ushort* Vsb = &Vs[buf][0];

        f32x4 s[4];
#pragma unroll
        for (int t = 0; t < 4; ++t) {
            const int rbyte = (t * 16 + lr) * 128;
            const short8 kb0 = *reinterpret_cast<const short8*>(
                &Ksb[(rbyte + ((lc * 16) ^ sw_w)) >> 1]);
            const short8 kb1 = *reinterpret_cast<const short8*>(
                &Ksb[(rbyte + ((64 + lc * 16) ^ sw_w)) >> 1]);
            f32x4 a = (f32x4)0.0f;
            a = __builtin_amdgcn_mfma_f32_16x16x32_bf16(kb0, qa0, a, 0, 0, 0);
            a = __builtin_amdgcn_mfma_f32_16x16x32_bf16(kb1, qa1, a, 0, 0, 0);
            s[t] = a;
        }

        float tmax = -1e30f;
#pragma unroll
        for (int t = 0; t < 4; ++t)
#pragma unroll
            for (int r = 0; r < 4; ++r) {
                if (MASK) {
                    const int kl = t * 16 + lc * 4 + r;
                    if (kl > w * 16 + lr) s[t][r] = -1e30f;
                }
                tmax = fmaxf(tmax, s[t][r]);
            }
        tmax = fmaxf(tmax, __shfl_xor(tmax, 16));
        tmax = fmaxf(tmax, __shfl_xor(tmax, 32));

        if (!__all(tmax <= m_run + 8.0f)) {
            const float mnew = fmaxf(m_run, tmax);
            const float corr = __builtin_amdgcn_exp2f(m_run - mnew);
            m_run = mnew;
            l_run *= corr;
            float cr[4];
#pragma unroll
            for (int r = 0; r < 4; ++r) cr[r] = __shfl(corr, lc * 4 + r, 16);
#pragma unroll
            for (int t = 0; t < 4; ++t)
#pragma unroll
                for (int r = 0; r < 4; ++r) acc_o[t][r] *= cr[r];
        }

        float rsum = 0.0f;
#pragma unroll
        for (int t = 0; t < 4; ++t) {
#pragma unroll
            for (int r = 0; r < 4; ++r) {
                const float p = __builtin_amdgcn_exp2f(s[t][r] - m_run);
                s[t][r] = p;
                rsum += p;
            }
            const unsigned lo = packbf(s[t][0], s[t][1]);
            const unsigned hi = packbf(s[t][2], s[t][3]);
            *reinterpret_cast<uint2*>(
                &Pw[(lr * 128 + ((t * 32 + lc * 8) ^ sw_w)) >> 1]) =
                make_uint2(lo, hi);
        }
        rsum += __shfl_xor(rsum, 16);
        rsum += __shfl_xor(rsum, 32);
        l_run += rsum;

        const short8 pa0 = *reinterpret_cast<const short8*>(
            &Pw[(lr * 128 + ((lc * 16) ^ sw_w)) >> 1]);
        const short8 pa1 = *reinterpret_cast<const short8*>(
            &Pw[(lr * 128 + ((64 + lc * 16) ^ sw_w)) >> 1]);

#pragma unroll
        for (int t = 0; t < 4; ++t) {
            const int rbyte = (t * 16 + lr) * 128;
            const short8 vb0 = *reinterpret_cast<const short8*>(
                &Vsb[(rbyte + ((lc * 16) ^ sw_w)) >> 1]);
            const short8 vb1 = *reinterpret_cast<const short8*>(
                &Vsb[(rbyte + ((64 + lc * 16) ^ sw_w)) >> 1]);
            acc_o[t] = __builtin_amdgcn_mfma_f32_16x16x32_bf16(
                    pa0, vb0, acc_o[t], 0, 0, 0);
            acc_o[t] = __builtin_amdgcn_mfma_f32_16x16x32_bf16(
                    pa1, vb1, acc_o[t], 0, 0, 0);
        }
    };

    int buf = 0;
    for (int it = 0; it < nt - 1; ++it) {
        const int kn = (it + 1) * 64;
#pragma unroll
        for (int cc = 0; cc < 2; ++cc) {
            const int c = w + cc * 4;
            gload16(Kbase + (size_t)(kn + c * 8 + rsub) * D_KK + csw,
                    &Ks[buf ^ 1][c * 512]);
            gload16(Vbase + (size_t)(c * 8 + rsub) * SEQ + kn + csw,
                    &Vs[buf ^ 1][c * 512]);
        }
        tile_body(buf, std::integral_constant<bool, false>{});
        __syncthreads();
        buf ^= 1;
    }
    tile_body(buf, std::integral_constant<bool, true>{});

    const float linv = 1.0f / l_run;
    float invr[4];
#pragma unroll
    for (int r = 0; r < 4; ++r) invr[r] = __shfl(linv, lc * 4 + r, 16);
#pragma unroll
    for (int r = 0; r < 4; ++r) {
        const int qrow = qr0 + lc * 4 + r;
        ushort* Op = Ob + ((size_t)b * SEQ + qrow) * D_MODEL + h * D_KK;
#pragma unroll
        for (int t = 0; t < 4; ++t)
            Op[t * 16 + lr] = f2bf(acc_o[t][r] * invr[r]);
    }
}

// ---------------------------------------------------------------------------
extern "C" void kernel_launch(void* const* d_in, const int* in_sizes, int n_in,
                              void* d_out, int out_size, void* d_ws, size_t ws_size,
                              hipStream_t stream)
{
    const float* x  = (const float*)d_in[0];
    const float* Wq = (const float*)d_in[2];
    const float* bq = (const float*)d_in[3];
    const float* Wk = (const float*)d_in[4];
    const float* bk = (const float*)d_in[5];
    const float* Wv = (const float*)d_in[6];
    const float* bv = (const float*)d_in[7];
    const float* Wo = (const float*)d_in[8];
    const float* bo = (const float*)d_in[9];
    float* out = (float*)d_out;

    const size_t TSZ = (size_t)M_TOTAL * D_MODEL;
    const size_t WSZ = (size_t)D_MODEL * D_MODEL;
    ushort* xb  = (ushort*)d_ws;
    ushort* Wqb = xb  + TSZ;
    ushort* Wkb = Wqb + WSZ;
    ushort* Wvb = Wkb + WSZ;
    ushort* Wob = Wvb + WSZ;
    ushort* Qb  = Wob + WSZ;
    ushort* Kb  = Qb  + TSZ;
    ushort* Vt  = Kb  + TSZ;
    ushort* Ob  = Vt  + TSZ;

    dim3 blk(256);
    cvt_kernel<<<dim3(256, 5), blk, 0, stream>>>(x, Wq, Wk, Wv, Wo,
                                                 xb, Wqb, Wkb, Wvb, Wob);

    // QKV: 32 mt x 16 nt x 3 z = 1536 blocks (flat, XCD-chunked decode)
    gemm_mfma<1><<<dim3(1536), blk, 0, stream>>>(xb, Wqb, bq, Qb,
                                                     Wkb, bk, Kb,
                                                     Wvb, bv, Vt);

    attn_mfma_kernel<<<dim3(1024), blk, 0, stream>>>(Qb, Kb, Vt, Ob);

    // O-proj: 32 mt x 16 nt = 512 blocks
    gemm_mfma<0><<<dim3(512), blk, 0, stream>>>(Ob, Wob, bo, out,
                                                    Wob, bo, out,
                                                    Wob, bo, out);
}